// Round 11
// baseline (343.105 us; speedup 1.0000x reference)
//
#include <hip/hip_runtime.h>
#include <hip/hip_bf16.h>

// QDense: out = s * (U X U^H)[:128,:128] / tr + (1-s) * diag(softmax(rand_w))
// B=512, D=256, O=128.
// Round-11 = r9/r10 dataflow with a 4-DEEP named-scalar X ring (and matched
// 4-deep Q ring) at 1 block/CU:
//   - X: global->reg direct (fragment order), slot = P&3, reissue P+4 after
//     consume.  In-flight 4 slices x 2KB x 8 waves = 68KB/CU -> latency covered.
//   - Q(S) issued right after X(S): any vmcnt wait drains only slices <= P.
//   - Trace unconditional on all 8 waves (no divergent loads -> tight static
//     vmcnt); block diag-sum = 2x trace, halved in epilogue.
//   - __launch_bounds__(512,2): allocator cap ~256 unified, no spill (r10: (512,4)
//     clamps to 64 and spills; r9/r1 prove (512,2) safe).
// U-half: swizzled LDS 64KB.  Yt: 16KB.  Total 80KB.
// Raw s_barrier + lgkmcnt(0) only (2 per jt-step); vmcnt stays counted.
// 1024 blocks (b = bx>>1, k'-half kh = bx&1), 512 thr.

typedef __attribute__((ext_vector_type(4))) float f32x4;
typedef __attribute__((ext_vector_type(8))) short bf16x8;

static __device__ __forceinline__ short f2bf(float f) {   // prep kernels only
    unsigned u = __float_as_uint(f);
    u += 0x7fffu + ((u >> 16) & 1u);
    return (short)(u >> 16);
}

static __device__ __forceinline__ unsigned cvtpk2(float lo, float hi) {
    union { __hip_bfloat162 h; unsigned u; } c;
    c.h = __float22bfloat162_rn(float2{lo, hi});
    return c.u;
}

static __device__ __forceinline__ bf16x8 pack8(f32x4 a, f32x4 b) {
    union { unsigned u[4]; bf16x8 v; } r;
    r.u[0] = cvtpk2(a[0], a[1]);
    r.u[1] = cvtpk2(a[2], a[3]);
    r.u[2] = cvtpk2(b[0], b[1]);
    r.u[3] = cvtpk2(b[2], b[3]);
    return r.v;
}

static __device__ __forceinline__ f32x4 mfma16(bf16x8 a, bf16x8 b, f32x4 c) {
    return __builtin_amdgcn_mfma_f32_16x16x32_bf16(a, b, c, 0, 0, 0);
}

// slice S = (jt = S>>3, ks = S&7) offset from per-lane base, in ELEMENTS
// (floats for X, shorts for Q; both have row stride 256 elements)
#define XGOFF(S) ((((S) >> 3) & 3) * 16384 + ((S) & 7) * 32)

// ---- prep kernels (r3 verbatim) ----
__global__ void qprep_u(const float* __restrict__ wt,
                        short* __restrict__ Ur, short* __restrict__ Ui) {
    int idx = blockIdx.x * 256 + threadIdx.x;
    float2 v = ((const float2*)wt)[idx];
    Ur[idx] = f2bf(v.x);
    Ui[idx] = f2bf(v.y);
}

__global__ void qprep_ps(const float* __restrict__ rw, const float* __restrict__ lm,
                         float* __restrict__ pv, float* __restrict__ sv) {
    int t = threadIdx.x;
    float w0 = rw[t], w1 = rw[t + 64];
    float m = fmaxf(w0, w1);
    #pragma unroll
    for (int o = 32; o > 0; o >>= 1) m = fmaxf(m, __shfl_xor(m, o));
    float e0 = expf(w0 - m), e1 = expf(w1 - m);
    float ss = e0 + e1;
    #pragma unroll
    for (int o = 32; o > 0; o >>= 1) ss += __shfl_xor(ss, o);
    pv[t] = e0 / ss;
    pv[t + 64] = e1 / ss;
    if (t == 0) sv[0] = 1.f / (1.f + expf(-lm[0]));
}

__global__ void qprep_q(const float* __restrict__ wt,
                        short* __restrict__ Qrb, short* __restrict__ Qib) {
    int j = blockIdx.x;
    int k = threadIdx.x;
    float ar = 0.f, ai = 0.f;
    for (int i = 0; i < 128; ++i) {
        float2 uk = ((const float2*)wt)[i * 256 + k];
        float2 uj = ((const float2*)wt)[i * 256 + j];
        ar += uk.x * uj.x + uk.y * uj.y;
        ai += uk.x * uj.y - uk.y * uj.x;
    }
    Qrb[j * 256 + k] = f2bf(ar);
    Qib[j * 256 + k] = f2bf(ai);
}

// ---- pipeline macros (P is a LITERAL) ----
#define ISSUE_X(S, a, b, c, d) do {                                             \
    a = *(const f32x4*)(xr + xoff + XGOFF(S));                                  \
    b = *(const f32x4*)(xr + xoff + XGOFF(S) + 4);                              \
    c = *(const f32x4*)(xi + xoff + XGOFF(S));                                  \
    d = *(const f32x4*)(xi + xoff + XGOFF(S) + 4);                              \
} while (0)

#define ISSUE_Q(S, qrv, qiv) do {                                               \
    qrv = *(const bf16x8*)(Qrb + qoff + XGOFF(S));                              \
    qiv = *(const bf16x8*)(Qib + qoff + XGOFF(S));                              \
} while (0)

#define PHASE(P, xa, xb, xc, xd, qrv, qiv) do {                                 \
    bf16x8 axr = pack8(xa, xb);          /* vmcnt wait lands here */            \
    bf16x8 axi = pack8(xc, xd);                                                 \
    if ((P) + 4 < 32) ISSUE_X((P) + 4, xa, xb, xc, xd);                         \
    __builtin_amdgcn_sched_barrier(0);   /* pin issues above MFMAs */           \
    bf16x8 axrn = axr ^ (short)0x8000;                                          \
    {                                                                           \
        const int uo = uoA + (((((P) & 7) * 64) + g16) ^ swA);                  \
        bf16x8 bur = *(const bf16x8*)(smem + uo);                               \
        bf16x8 bui = *(const bf16x8*)(smem + 32768 + uo);                       \
        yR0 = mfma16(axr,  bur, yR0);                                           \
        yR0 = mfma16(axi,  bui, yR0);                                           \
        yI0 = mfma16(axi,  bur, yI0);                                           \
        yI0 = mfma16(axrn, bui, yI0);                                           \
    }                                                                           \
    {                                                                           \
        const int uo = uoB + (((((P) & 7) * 64) + g16) ^ swB);                  \
        bf16x8 bur = *(const bf16x8*)(smem + uo);                               \
        bf16x8 bui = *(const bf16x8*)(smem + 32768 + uo);                       \
        yR1 = mfma16(axr,  bur, yR1);                                           \
        yR1 = mfma16(axi,  bui, yR1);                                           \
        yI1 = mfma16(axi,  bur, yI1);                                           \
        yI1 = mfma16(axrn, bui, yI1);                                           \
    }                                                                           \
    {                                                                           \
        bf16x8 axin = axi ^ (short)0x8000;                                      \
        tr4 = mfma16(axr,  qrv, tr4);                                           \
        tr4 = mfma16(axin, qiv, tr4);                                           \
    }                                                                           \
    if ((P) + 4 < 32) ISSUE_Q((P) + 4, qrv, qiv);                               \
} while (0)

#define PH0(P) PHASE(P, g00, g01, g02, g03, q0r, q0i)
#define PH1(P) PHASE(P, g10, g11, g12, g13, q1r, q1i)
#define PH2(P) PHASE(P, g20, g21, g22, g23, q2r, q2i)
#define PH3(P) PHASE(P, g30, g31, g32, g33, q3r, q3i)

// ---- stage B for one jt (all-scalar accumulators, index addressing) ----
#define STAGEB_KS(JT, KS2) do {                                                 \
    const int ub = (JT) * 64 + (KS2) * 32 + g8;                                 \
    bf16x8 aur0 = *(const bf16x8*)(Urg + ib0 * 256 + ub);                       \
    bf16x8 aui0 = *(const bf16x8*)(Uig + ib0 * 256 + ub);                       \
    bf16x8 aur1 = *(const bf16x8*)(Urg + ib1 * 256 + ub);                       \
    bf16x8 aui1 = *(const bf16x8*)(Uig + ib1 * 256 + ub);                       \
    bf16x8 auin0 = aui0 ^ (short)0x8000;                                        \
    bf16x8 auin1 = aui1 ^ (short)0x8000;                                        \
    {                                                                           \
        const int off = ybA + (((KS2) * 64 + g16) ^ ysA);                       \
        bf16x8 byr = *(const bf16x8*)(smem + 65536 + off);                      \
        bf16x8 byi = *(const bf16x8*)(smem + 73728 + off);                      \
        sR00 = mfma16(aur0,  byr, sR00); sR00 = mfma16(auin0, byi, sR00);       \
        sI00 = mfma16(aui0,  byr, sI00); sI00 = mfma16(aur0,  byi, sI00);       \
        sR10 = mfma16(aur1,  byr, sR10); sR10 = mfma16(auin1, byi, sR10);       \
        sI10 = mfma16(aui1,  byr, sI10); sI10 = mfma16(aur1,  byi, sI10);       \
    }                                                                           \
    {                                                                           \
        const int off = ybB + (((KS2) * 64 + g16) ^ ysB);                       \
        bf16x8 byr = *(const bf16x8*)(smem + 65536 + off);                      \
        bf16x8 byi = *(const bf16x8*)(smem + 73728 + off);                      \
        sR01 = mfma16(aur0,  byr, sR01); sR01 = mfma16(auin0, byi, sR01);       \
        sI01 = mfma16(aui0,  byr, sI01); sI01 = mfma16(aur0,  byi, sI01);       \
        sR11 = mfma16(aur1,  byr, sR11); sR11 = mfma16(auin1, byi, sR11);       \
        sI11 = mfma16(aui1,  byr, sI11); sI11 = mfma16(aur1,  byi, sI11);       \
    }                                                                           \
} while (0)

// ---- Yt exchange + stage B ----
#define YT_AND_B(JT) do {                                                       \
    __builtin_amdgcn_s_barrier();          /* stageB(prev) reads done */        \
    __builtin_amdgcn_sched_barrier(0);                                          \
    {                                                                           \
        uint2 v;                                                                \
        v.x = cvtpk2(yR0[0], yR0[1]); v.y = cvtpk2(yR0[2], yR0[3]);             \
        *(uint2*)(smem + 65536 + woA) = v;                                      \
        v.x = cvtpk2(yI0[0], yI0[1]); v.y = cvtpk2(yI0[2], yI0[3]);             \
        *(uint2*)(smem + 73728 + woA) = v;                                      \
        v.x = cvtpk2(yR1[0], yR1[1]); v.y = cvtpk2(yR1[2], yR1[3]);             \
        *(uint2*)(smem + 65536 + woB) = v;                                      \
        v.x = cvtpk2(yI1[0], yI1[1]); v.y = cvtpk2(yI1[2], yI1[3]);             \
        *(uint2*)(smem + 73728 + woB) = v;                                      \
    }                                                                           \
    asm volatile("s_waitcnt lgkmcnt(0)" ::: "memory");                          \
    __builtin_amdgcn_sched_barrier(0);                                          \
    __builtin_amdgcn_s_barrier();                                               \
    __builtin_amdgcn_sched_barrier(0);                                          \
    STAGEB_KS(JT, 0);                                                           \
    STAGEB_KS(JT, 1);                                                           \
    yR0 = zero; yR1 = zero; yI0 = zero; yI1 = zero;                             \
} while (0)

// ---- main fused kernel ----
__global__ __launch_bounds__(512, 2) void qfused(
    const float* __restrict__ xr, const float* __restrict__ xi,
    const short* __restrict__ Urg, const short* __restrict__ Uig,
    const short* __restrict__ Qrb, const short* __restrict__ Qib,
    const float* __restrict__ pv, const float* __restrict__ sv,
    float* __restrict__ out)
{
    // LDS: [0,65536) U-half swizzled (R 0, I 32768); [65536,81920) Yt (R/I).
    __shared__ __align__(16) char smem[81920];

    const int bx   = blockIdx.x;
    const int b    = bx >> 1;
    const int kh   = bx & 1;
    const int tid  = threadIdx.x;
    const int lane = tid & 63;
    const int w    = tid >> 6;
    const int c16  = lane & 15;
    const int g4   = lane >> 4;
    const int g8   = g4 * 8;
    const int g16  = g4 * 16;

    // ---- stage U-half into swizzled LDS (r3-proven) ----
    #pragma unroll
    for (int q = 0; q < 4; ++q) {
        int c    = tid + q * 512;
        int row  = c >> 5;
        int slot = c & 31;
        int ss   = slot ^ (row & 7);
        const short* sr = Urg + (size_t)(kh * 64 + row) * 256 + ss * 8;
        const short* si = Uig + (size_t)(kh * 64 + row) * 256 + ss * 8;
        *(bf16x8*)(smem + row * 512 + slot * 16)         = *(const bf16x8*)sr;
        *(bf16x8*)(smem + 32768 + row * 512 + slot * 16) = *(const bf16x8*)si;
    }

    const int  ja   = (w & 3) * 16;      // stage-A j-group
    const int  kb   = (w >> 2) * 32;     // stage-A k'-group
    const int  wm   = w >> 1;            // stage-B i-quarter
    const int  wn   = w & 1;             // stage-B k'-half-of-half

    // shared int offsets over uniform bases (saddr-form loads)
    const int xoff = (b << 16) + (ja + c16) * 256 + g8;
    const int qoff = (ja + c16) * 256 + g8;

    // precomputed LDS offset parts
    const int klA = kb + c16,      klB = kb + 16 + c16;
    const int uoA = klA * 512,     uoB = klB * 512;       // U row bases
    const int swA = (klA & 7) << 4, swB = (klB & 7) << 4; // swizzle keys
    const int ybA = (wn * 32 + c16) * 128;                // stage-B Yt rows
    const int ybB = (wn * 32 + 16 + c16) * 128;
    const int ysA = ((wn * 32 + c16) & 7) << 4;
    const int ysB = ((wn * 32 + 16 + c16) & 7) << 4;
    const int woA = klA * 128 + ((ja * 2 + g8) ^ swA);    // Yt write offs
    const int woB = klB * 128 + ((ja * 2 + g8) ^ swB);
    const int ib0 = wm * 32 + c16, ib1 = wm * 32 + 16 + c16;

    f32x4 zero = {0.f, 0.f, 0.f, 0.f};
    f32x4 sR00 = zero, sR01 = zero, sR10 = zero, sR11 = zero;
    f32x4 sI00 = zero, sI01 = zero, sI10 = zero, sI11 = zero;
    f32x4 tr4 = zero;
    f32x4 yR0 = zero, yR1 = zero, yI0 = zero, yI1 = zero;

    // 4-slot X ring + 4-slot Q ring (all named scalars; slot = P&3)
    f32x4 g00, g01, g02, g03;
    f32x4 g10, g11, g12, g13;
    f32x4 g20, g21, g22, g23;
    f32x4 g30, g31, g32, g33;
    bf16x8 q0r, q0i, q1r, q1i, q2r, q2i, q3r, q3i;

    // ---- prologue: issue slices 0..3 (X then Q each, matching steady FIFO) ----
    ISSUE_X(0, g00, g01, g02, g03);  ISSUE_Q(0, q0r, q0i);
    ISSUE_X(1, g10, g11, g12, g13);  ISSUE_Q(1, q1r, q1i);
    ISSUE_X(2, g20, g21, g22, g23);  ISSUE_Q(2, q2r, q2i);
    ISSUE_X(3, g30, g31, g32, g33);  ISSUE_Q(3, q3r, q3i);
    asm volatile("s_waitcnt lgkmcnt(0)" ::: "memory");   // U ds_writes done
    __builtin_amdgcn_sched_barrier(0);
    __builtin_amdgcn_s_barrier();                        // vmcnt stays counted
    __builtin_amdgcn_sched_barrier(0);

    PH0(0);  PH1(1);  PH2(2);  PH3(3);  PH0(4);  PH1(5);  PH2(6);  PH3(7);
    YT_AND_B(0);
    PH0(8);  PH1(9);  PH2(10); PH3(11); PH0(12); PH1(13); PH2(14); PH3(15);
    YT_AND_B(1);
    PH0(16); PH1(17); PH2(18); PH3(19); PH0(20); PH1(21); PH2(22); PH3(23);
    YT_AND_B(2);
    PH0(24); PH1(25); PH2(26); PH3(27); PH0(28); PH1(29); PH2(30); PH3(31);
    YT_AND_B(3);

    // ---- trace: all 8 waves traced all rows -> block diag-sum = 2x trace ----
    float loc = ((c16 >> 2) == g4) ? tr4[c16 & 3] : 0.f;
    #pragma unroll
    for (int o = 32; o > 0; o >>= 1) loc += __shfl_xor(loc, o);
    __syncthreads();                      // Yt dead; reuse for reduction
    float* red = (float*)(smem + 65536);
    if (lane == 0) red[w] = loc;
    __syncthreads();
    float tr = 0.5f * (red[0] + red[1] + red[2] + red[3] +
                       red[4] + red[5] + red[6] + red[7]);

    float s     = sv[0];
    float inv   = s / tr;
    float onems = 1.f - s;
    float* outr = out + (size_t)b * 16384;
    float* outi = out + 8388608 + (size_t)b * 16384;

    #define EPI(SRV, SIV, MT, NT) do {                                          \
        int colc = kh * 64 + wn * 32 + (NT) * 16 + c16;                         \
        _Pragma("unroll")                                                       \
        for (int r = 0; r < 4; ++r) {                                           \
            int row = wm * 32 + (MT) * 16 + g4 * 4 + r;                         \
            float vr = SRV[r] * inv;                                            \
            if (row == colc) vr += onems * pv[row];                             \
            outr[row * 128 + colc] = vr;                                        \
            outi[row * 128 + colc] = SIV[r] * inv;                              \
        }                                                                       \
    } while (0)

    EPI(sR00, sI00, 0, 0);
    EPI(sR01, sI01, 0, 1);
    EPI(sR10, sI10, 1, 0);
    EPI(sR11, sI11, 1, 1);
    #undef EPI
}

extern "C" void kernel_launch(void* const* d_in, const int* in_sizes, int n_in,
                              void* d_out, int out_size, void* d_ws, size_t ws_size,
                              hipStream_t stream) {
    (void)in_sizes; (void)n_in; (void)out_size; (void)ws_size;
    const float* xr = (const float*)d_in[0];
    const float* xi = (const float*)d_in[1];
    const float* wt = (const float*)d_in[2];
    const float* rw = (const float*)d_in[3];
    const float* lm = (const float*)d_in[4];

    short* Ur  = (short*)d_ws;                        // 128x256 bf16 (64 KB)
    short* Ui  = Ur + 32768;                          // 64 KB
    float* pv  = (float*)((char*)d_ws + 131072);      // 128 f32
    float* sv  = pv + 128;                            // 1 f32
    short* Qrb = (short*)((char*)d_ws + 135168);      // 256x256 bf16 (128 KB)
    short* Qib = (short*)((char*)d_ws + 266240);      // 128 KB
    float* o   = (float*)d_out;

    qprep_u<<<dim3(128), dim3(256), 0, stream>>>(wt, Ur, Ui);
    qprep_ps<<<dim3(1), dim3(64), 0, stream>>>(rw, lm, pv, sv);
    qprep_q<<<dim3(256), dim3(256), 0, stream>>>(wt, Qrb, Qib);
    qfused<<<dim3(1024), dim3(512), 0, stream>>>(xr, xi, Ur, Ui, Qrb, Qib, pv, sv, o);
}

// Round 12
// 252.460 us; speedup vs baseline: 1.3590x; 1.3590x over previous
//
#include <hip/hip_runtime.h>
#include <hip/hip_bf16.h>

// QDense: out = s * (U X U^H)[:128,:128] / tr + (1-s) * diag(softmax(rand_w))
// B=512, D=256, O=128.
// Round-12: X staged via __builtin_amdgcn_global_load_lds (zero VGPR cost)
// into 4 LDS slots (4-deep pipeline), counted vmcnt (never 0 in loop), raw
// s_barrier per phase.  Each slice staged ONCE cooperatively (wave w stages
// rows w*8..+8; 2 glds/wave/phase).  Bank-conflict-free reads via SOURCE
// address pre-permutation (LDS dest stays linear as glds requires).
// LDS: U-half 64KB + Yt 16KB + X 4x16KB = 144KB -> 1 block/CU, 8 waves.
// 1024 blocks (b = bx>>1, k'-half kh = bx&1), 512 thr.
// Trace via Q = (U_sub^H U_sub)^T on all 8 waves (2x trace, halved at end).

typedef __attribute__((ext_vector_type(4))) float f32x4;
typedef __attribute__((ext_vector_type(8))) short bf16x8;

static __device__ __forceinline__ short f2bf(float f) {   // prep kernels only
    unsigned u = __float_as_uint(f);
    u += 0x7fffu + ((u >> 16) & 1u);
    return (short)(u >> 16);
}

static __device__ __forceinline__ unsigned cvtpk2(float lo, float hi) {
    union { __hip_bfloat162 h; unsigned u; } c;
    c.h = __float22bfloat162_rn(float2{lo, hi});
    return c.u;
}

static __device__ __forceinline__ bf16x8 pack8(f32x4 a, f32x4 b) {
    union { unsigned u[4]; bf16x8 v; } r;
    r.u[0] = cvtpk2(a[0], a[1]);
    r.u[1] = cvtpk2(a[2], a[3]);
    r.u[2] = cvtpk2(b[0], b[1]);
    r.u[3] = cvtpk2(b[2], b[3]);
    return r.v;
}

static __device__ __forceinline__ f32x4 mfma16(bf16x8 a, bf16x8 b, f32x4 c) {
    return __builtin_amdgcn_mfma_f32_16x16x32_bf16(a, b, c, 0, 0, 0);
}

// slice S = (jt = S>>3, ks = S&7) offset in ELEMENTS (floats X / shorts Q)
#define XGOFF(S) ((((S) >> 3) & 3) * 16384 + ((S) & 7) * 32)
#define XB 81920                         // X region base in LDS

// ---- prep kernels (r3 verbatim) ----
__global__ void qprep_u(const float* __restrict__ wt,
                        short* __restrict__ Ur, short* __restrict__ Ui) {
    int idx = blockIdx.x * 256 + threadIdx.x;
    float2 v = ((const float2*)wt)[idx];
    Ur[idx] = f2bf(v.x);
    Ui[idx] = f2bf(v.y);
}

__global__ void qprep_ps(const float* __restrict__ rw, const float* __restrict__ lm,
                         float* __restrict__ pv, float* __restrict__ sv) {
    int t = threadIdx.x;
    float w0 = rw[t], w1 = rw[t + 64];
    float m = fmaxf(w0, w1);
    #pragma unroll
    for (int o = 32; o > 0; o >>= 1) m = fmaxf(m, __shfl_xor(m, o));
    float e0 = expf(w0 - m), e1 = expf(w1 - m);
    float ss = e0 + e1;
    #pragma unroll
    for (int o = 32; o > 0; o >>= 1) ss += __shfl_xor(ss, o);
    pv[t] = e0 / ss;
    pv[t + 64] = e1 / ss;
    if (t == 0) sv[0] = 1.f / (1.f + expf(-lm[0]));
}

__global__ void qprep_q(const float* __restrict__ wt,
                        short* __restrict__ Qrb, short* __restrict__ Qib) {
    int j = blockIdx.x;
    int k = threadIdx.x;
    float ar = 0.f, ai = 0.f;
    for (int i = 0; i < 128; ++i) {
        float2 uk = ((const float2*)wt)[i * 256 + k];
        float2 uj = ((const float2*)wt)[i * 256 + j];
        ar += uk.x * uj.x + uk.y * uj.y;
        ai += uk.x * uj.y - uk.y * uj.x;
    }
    Qrb[j * 256 + k] = f2bf(ar);
    Qib[j * 256 + k] = f2bf(ai);
}

// ---- DMA-issue slice S into LDS slot S&3 (2 glds; dest wave-uniform) ----
#define ISSUE_SLICE(S) do {                                                     \
    __builtin_amdgcn_global_load_lds(                                           \
        (const __attribute__((address_space(1))) void*)(xr + xbb + xsl + XGOFF(S)), \
        (__attribute__((address_space(3))) void*)(smem + XB + ((S) & 3) * 16384 + wq), \
        16, 0, 0);                                                              \
    __builtin_amdgcn_global_load_lds(                                           \
        (const __attribute__((address_space(1))) void*)(xi + xbb + xsl + XGOFF(S)), \
        (__attribute__((address_space(3))) void*)(smem + XB + ((S) & 3) * 16384 + 8192 + wq), \
        16, 0, 0);                                                              \
} while (0)

// ---- one phase (P, NV = vmcnt literal; QCR/QCI = Q slot P&3, QNR/QNI = (P+3)&3) ----
#define PHASE(P, NV, QCR, QCI, QNR, QNI) do {                                   \
    asm volatile("s_waitcnt vmcnt(" #NV ")" ::: "memory");                      \
    __builtin_amdgcn_sched_barrier(0);                                          \
    __builtin_amdgcn_s_barrier();                                               \
    __builtin_amdgcn_sched_barrier(0);                                          \
    const int xso = XB + ((P) & 3) * 16384 + xrdo;                              \
    f32x4 a0 = *(const f32x4*)(smem + xso + cs0);                               \
    f32x4 a1 = *(const f32x4*)(smem + xso + cs1);                               \
    f32x4 b0 = *(const f32x4*)(smem + xso + 8192 + cs0);                        \
    f32x4 b1 = *(const f32x4*)(smem + xso + 8192 + cs1);                        \
    if ((P) + 3 < 32) {                                                         \
        ISSUE_SLICE((P) + 3);                                                   \
        QNR = *(const bf16x8*)(Qrb + qoff + XGOFF((P) + 3));                    \
        QNI = *(const bf16x8*)(Qib + qoff + XGOFF((P) + 3));                    \
    }                                                                           \
    bf16x8 axr  = pack8(a0, a1);                                                \
    bf16x8 axi  = pack8(b0, b1);                                                \
    bf16x8 axrn = axr ^ (short)0x8000;                                          \
    {                                                                           \
        const int uo = uoA + (((((P) & 7) * 64) + g16) ^ swA);                  \
        bf16x8 bur = *(const bf16x8*)(smem + uo);                               \
        bf16x8 bui = *(const bf16x8*)(smem + 32768 + uo);                       \
        yR0 = mfma16(axr,  bur, yR0);                                           \
        yR0 = mfma16(axi,  bui, yR0);                                           \
        yI0 = mfma16(axi,  bur, yI0);                                           \
        yI0 = mfma16(axrn, bui, yI0);                                           \
    }                                                                           \
    {                                                                           \
        const int uo = uoB + (((((P) & 7) * 64) + g16) ^ swB);                  \
        bf16x8 bur = *(const bf16x8*)(smem + uo);                               \
        bf16x8 bui = *(const bf16x8*)(smem + 32768 + uo);                       \
        yR1 = mfma16(axr,  bur, yR1);                                           \
        yR1 = mfma16(axi,  bui, yR1);                                           \
        yI1 = mfma16(axi,  bur, yI1);                                           \
        yI1 = mfma16(axrn, bui, yI1);                                           \
    }                                                                           \
    {                                                                           \
        bf16x8 axin = axi ^ (short)0x8000;                                      \
        tr4 = mfma16(axr,  QCR, tr4);                                           \
        tr4 = mfma16(axin, QCI, tr4);                                           \
    }                                                                           \
} while (0)

#define PH0(P, NV) PHASE(P, NV, q0r, q0i, q3r, q3i)
#define PH1(P, NV) PHASE(P, NV, q1r, q1i, q0r, q0i)
#define PH2(P, NV) PHASE(P, NV, q2r, q2i, q1r, q1i)
#define PH3(P, NV) PHASE(P, NV, q3r, q3i, q2r, q2i)

// ---- stage B for one jt (r9-proven, all-scalar accs) ----
#define STAGEB_KS(JT, KS2) do {                                                 \
    const int ub = (JT) * 64 + (KS2) * 32 + g8;                                 \
    bf16x8 aur0 = *(const bf16x8*)(Urg + ib0 * 256 + ub);                       \
    bf16x8 aui0 = *(const bf16x8*)(Uig + ib0 * 256 + ub);                       \
    bf16x8 aur1 = *(const bf16x8*)(Urg + ib1 * 256 + ub);                       \
    bf16x8 aui1 = *(const bf16x8*)(Uig + ib1 * 256 + ub);                       \
    bf16x8 auin0 = aui0 ^ (short)0x8000;                                        \
    bf16x8 auin1 = aui1 ^ (short)0x8000;                                        \
    {                                                                           \
        const int off = ybA + (((KS2) * 64 + g16) ^ ysA);                       \
        bf16x8 byr = *(const bf16x8*)(smem + 65536 + off);                      \
        bf16x8 byi = *(const bf16x8*)(smem + 73728 + off);                      \
        sR00 = mfma16(aur0,  byr, sR00); sR00 = mfma16(auin0, byi, sR00);       \
        sI00 = mfma16(aui0,  byr, sI00); sI00 = mfma16(aur0,  byi, sI00);       \
        sR10 = mfma16(aur1,  byr, sR10); sR10 = mfma16(auin1, byi, sR10);       \
        sI10 = mfma16(aui1,  byr, sI10); sI10 = mfma16(aur1,  byi, sI10);       \
    }                                                                           \
    {                                                                           \
        const int off = ybB + (((KS2) * 64 + g16) ^ ysB);                       \
        bf16x8 byr = *(const bf16x8*)(smem + 65536 + off);                      \
        bf16x8 byi = *(const bf16x8*)(smem + 73728 + off);                      \
        sR01 = mfma16(aur0,  byr, sR01); sR01 = mfma16(auin0, byi, sR01);       \
        sI01 = mfma16(aui0,  byr, sI01); sI01 = mfma16(aur0,  byi, sI01);       \
        sR11 = mfma16(aur1,  byr, sR11); sR11 = mfma16(auin1, byi, sR11);       \
        sI11 = mfma16(aui1,  byr, sI11); sI11 = mfma16(aur1,  byi, sI11);       \
    }                                                                           \
} while (0)

// ---- Yt exchange + stage B (vmcnt NOT drained; lgkmcnt only) ----
#define YT_AND_B(JT) do {                                                       \
    __builtin_amdgcn_s_barrier();          /* stageB(prev) reads done */        \
    __builtin_amdgcn_sched_barrier(0);                                          \
    {                                                                           \
        uint2 v;                                                                \
        v.x = cvtpk2(yR0[0], yR0[1]); v.y = cvtpk2(yR0[2], yR0[3]);             \
        *(uint2*)(smem + 65536 + woA) = v;                                      \
        v.x = cvtpk2(yI0[0], yI0[1]); v.y = cvtpk2(yI0[2], yI0[3]);             \
        *(uint2*)(smem + 73728 + woA) = v;                                      \
        v.x = cvtpk2(yR1[0], yR1[1]); v.y = cvtpk2(yR1[2], yR1[3]);             \
        *(uint2*)(smem + 65536 + woB) = v;                                      \
        v.x = cvtpk2(yI1[0], yI1[1]); v.y = cvtpk2(yI1[2], yI1[3]);             \
        *(uint2*)(smem + 73728 + woB) = v;                                      \
    }                                                                           \
    asm volatile("s_waitcnt lgkmcnt(0)" ::: "memory");                          \
    __builtin_amdgcn_sched_barrier(0);                                          \
    __builtin_amdgcn_s_barrier();                                               \
    __builtin_amdgcn_sched_barrier(0);                                          \
    STAGEB_KS(JT, 0);                                                           \
    STAGEB_KS(JT, 1);                                                           \
    yR0 = zero; yR1 = zero; yI0 = zero; yI1 = zero;                             \
} while (0)

// ---- main fused kernel ----
__global__ __launch_bounds__(512, 2) void qfused(
    const float* __restrict__ xr, const float* __restrict__ xi,
    const short* __restrict__ Urg, const short* __restrict__ Uig,
    const short* __restrict__ Qrb, const short* __restrict__ Qib,
    const float* __restrict__ pv, const float* __restrict__ sv,
    float* __restrict__ out)
{
    // [0,65536) U-half swizzled (R 0, I 32768); [65536,81920) Yt (R/I);
    // [81920,147456) X slots[4] x { R[64x128B], I[64x128B] }.
    __shared__ __align__(16) char smem[147456];

    const int bx   = blockIdx.x;
    const int b    = bx >> 1;
    const int kh   = bx & 1;
    const int tid  = threadIdx.x;
    const int lane = tid & 63;
    const int w    = tid >> 6;
    const int c16  = lane & 15;
    const int g4   = lane >> 4;
    const int g8   = g4 * 8;
    const int g16  = g4 * 16;

    // ---- stage U-half into swizzled LDS (r3-proven) ----
    #pragma unroll
    for (int q = 0; q < 4; ++q) {
        int c    = tid + q * 512;
        int row  = c >> 5;
        int slot = c & 31;
        int ss   = slot ^ (row & 7);
        const short* sr = Urg + (size_t)(kh * 64 + row) * 256 + ss * 8;
        const short* si = Uig + (size_t)(kh * 64 + row) * 256 + ss * 8;
        *(bf16x8*)(smem + row * 512 + slot * 16)         = *(const bf16x8*)sr;
        *(bf16x8*)(smem + 32768 + row * 512 + slot * 16) = *(const bf16x8*)si;
    }

    const int  ja   = (w & 3) * 16;      // stage-A j-group
    const int  kb   = (w >> 2) * 32;     // stage-A k'-group
    const int  wm   = w >> 1;            // stage-B i-quarter
    const int  wn   = w & 1;             // stage-B k'-half-of-half

    // glds write-side: wave w stages tile rows w*8..+8.  lane l covers
    // row w*8+(l>>3), LDS chunk-slot l&7; source chunk = (l&7)^((l>>3)&7)
    // (source permutation = read-side XOR swizzle; LDS dest stays linear).
    const int grow = lane >> 3;
    const int xsl  = (w * 8 + grow) * 256 + (((lane & 7) ^ grow) << 2);
    const int xbb  = b << 16;
    const int wq   = w * 1024;           // wave's rows at row*128 = w*8*128

    // read-side: row = ja+c16 (swizzle key c16&7), chunks g4*2, g4*2+1
    const int xrdo = (ja + c16) * 128;
    const int cs0  = (((g4 * 2)     ^ (c16 & 7)) << 4);
    const int cs1  = (((g4 * 2 + 1) ^ (c16 & 7)) << 4);

    const int qoff = (ja + c16) * 256 + g8;

    // U / Yt offsets (r9-proven)
    const int klA = kb + c16,       klB = kb + 16 + c16;
    const int uoA = klA * 512,      uoB = klB * 512;
    const int swA = (klA & 7) << 4, swB = (klB & 7) << 4;
    const int ybA = (wn * 32 + c16) * 128;
    const int ybB = (wn * 32 + 16 + c16) * 128;
    const int ysA = ((wn * 32 + c16) & 7) << 4;
    const int ysB = ((wn * 32 + 16 + c16) & 7) << 4;
    const int woA = klA * 128 + ((ja * 2 + g8) ^ swA);
    const int woB = klB * 128 + ((ja * 2 + g8) ^ swB);
    const int ib0 = wm * 32 + c16,  ib1 = wm * 32 + 16 + c16;

    f32x4 zero = {0.f, 0.f, 0.f, 0.f};
    f32x4 sR00 = zero, sR01 = zero, sR10 = zero, sR11 = zero;
    f32x4 sI00 = zero, sI01 = zero, sI10 = zero, sI11 = zero;
    f32x4 tr4 = zero;
    f32x4 yR0 = zero, yR1 = zero, yI0 = zero, yI1 = zero;
    bf16x8 q0r, q0i, q1r, q1i, q2r, q2i, q3r, q3i;

    // ---- prologue: DMA slices 0..2 + Q(0..2); U writes visible ----
    ISSUE_SLICE(0);
    q0r = *(const bf16x8*)(Qrb + qoff + XGOFF(0));
    q0i = *(const bf16x8*)(Qib + qoff + XGOFF(0));
    ISSUE_SLICE(1);
    q1r = *(const bf16x8*)(Qrb + qoff + XGOFF(1));
    q1i = *(const bf16x8*)(Qib + qoff + XGOFF(1));
    ISSUE_SLICE(2);
    q2r = *(const bf16x8*)(Qrb + qoff + XGOFF(2));
    q2i = *(const bf16x8*)(Qib + qoff + XGOFF(2));
    asm volatile("s_waitcnt lgkmcnt(0)" ::: "memory");   // U ds_writes done
    __builtin_amdgcn_sched_barrier(0);
    // phase 0's barrier publishes U; its vmcnt(8) confirms slice 0.

    PH0(0,8);  PH1(1,8);  PH2(2,8);  PH3(3,8);  PH0(4,8);  PH1(5,8);  PH2(6,8);  PH3(7,8);
    YT_AND_B(0);
    PH0(8,8);  PH1(9,8);  PH2(10,8); PH3(11,8); PH0(12,8); PH1(13,8); PH2(14,8); PH3(15,8);
    YT_AND_B(1);
    PH0(16,8); PH1(17,8); PH2(18,8); PH3(19,8); PH0(20,8); PH1(21,8); PH2(22,8); PH3(23,8);
    YT_AND_B(2);
    PH0(24,8); PH1(25,8); PH2(26,8); PH3(27,8); PH0(28,8); PH1(29,8); PH2(30,4); PH3(31,0);
    YT_AND_B(3);

    // ---- trace: every diag row counted twice (waves w and w+4) -> 0.5x ----
    float loc = ((c16 >> 2) == g4) ? tr4[c16 & 3] : 0.f;
    #pragma unroll
    for (int o = 32; o > 0; o >>= 1) loc += __shfl_xor(loc, o);
    __syncthreads();                      // Yt dead; reuse for reduction
    float* red = (float*)(smem + 65536);
    if (lane == 0) red[w] = loc;
    __syncthreads();
    float tr = 0.5f * (red[0] + red[1] + red[2] + red[3] +
                       red[4] + red[5] + red[6] + red[7]);

    float s     = sv[0];
    float inv   = s / tr;
    float onems = 1.f - s;
    float* outr = out + (size_t)b * 16384;
    float* outi = out + 8388608 + (size_t)b * 16384;

    #define EPI(SRV, SIV, MT, NT) do {                                          \
        int colc = kh * 64 + wn * 32 + (NT) * 16 + c16;                         \
        _Pragma("unroll")                                                       \
        for (int r = 0; r < 4; ++r) {                                           \
            int row = wm * 32 + (MT) * 16 + g4 * 4 + r;                         \
            float vr = SRV[r] * inv;                                            \
            if (row == colc) vr += onems * pv[row];                             \
            outr[row * 128 + colc] = vr;                                        \
            outi[row * 128 + colc] = SIV[r] * inv;                              \
        }                                                                       \
    } while (0)

    EPI(sR00, sI00, 0, 0);
    EPI(sR01, sI01, 0, 1);
    EPI(sR10, sI10, 1, 0);
    EPI(sR11, sI11, 1, 1);
    #undef EPI
}

extern "C" void kernel_launch(void* const* d_in, const int* in_sizes, int n_in,
                              void* d_out, int out_size, void* d_ws, size_t ws_size,
                              hipStream_t stream) {
    (void)in_sizes; (void)n_in; (void)out_size; (void)ws_size;
    const float* xr = (const float*)d_in[0];
    const float* xi = (const float*)d_in[1];
    const float* wt = (const float*)d_in[2];
    const float* rw = (const float*)d_in[3];
    const float* lm = (const float*)d_in[4];

    short* Ur  = (short*)d_ws;                        // 128x256 bf16 (64 KB)
    short* Ui  = Ur + 32768;                          // 64 KB
    float* pv  = (float*)((char*)d_ws + 131072);      // 128 f32
    float* sv  = pv + 128;                            // 1 f32
    short* Qrb = (short*)((char*)d_ws + 135168);      // 256x256 bf16 (128 KB)
    short* Qib = (short*)((char*)d_ws + 266240);      // 128 KB
    float* o   = (float*)d_out;

    qprep_u<<<dim3(128), dim3(256), 0, stream>>>(wt, Ur, Ui);
    qprep_ps<<<dim3(1), dim3(64), 0, stream>>>(rw, lm, pv, sv);
    qprep_q<<<dim3(256), dim3(256), 0, stream>>>(wt, Qrb, Qib);
    qfused<<<dim3(1024), dim3(512), 0, stream>>>(xr, xi, Ur, Ui, Qrb, Qib, pv, sv, o);
}